// Round 1
// baseline (681.039 us; speedup 1.0000x reference)
//
#include <hip/hip_runtime.h>
#include <hip/hip_bf16.h>
#include <stdint.h>

// Problem constants (QuantizedLinear_22849226015470)
#define MROWS 8192      // 4*2048 activation rows
#define K_TOT 4096      // in_features
#define N_TOT 4096      // out_features
// trellis: NB=65536 tiles (256 x 256), 32 x 16-bit words per tile (512 bits)
// state_t = 16-bit big-endian window starting at bit 2t (circular)

typedef __attribute__((ext_vector_type(8))) short bf16x8;
typedef __attribute__((ext_vector_type(4))) float f32x4;

#define GLB(p) ((const __attribute__((address_space(1))) void*)(p))
#define LDSP(p) ((__attribute__((address_space(3))) void*)(p))

// ---------------- Hadamard-128 rotate (FWHT), fp32 in -> bf16 out ----------
// One wave per 128-group: lane holds elements (lane, lane+64).
__global__ __launch_bounds__(256) void hadamard_k(const float* __restrict__ in,
                                                  __hip_bfloat16* __restrict__ xb) {
    const int lane = threadIdx.x & 63;
    const int wave = threadIdx.x >> 6;
    const long g = (long)blockIdx.x * 4 + wave;   // 262144 groups total
    const long base = g * 128;
    float a = in[base + lane];
    float b = in[base + 64 + lane];
    // stage s=64 (cross-half, lane-local)
    float ta = a + b;
    b = a - b;
    a = ta;
    // stages 32..1 via wave shuffles (identical pattern in both halves)
#pragma unroll
    for (int s = 32; s >= 1; s >>= 1) {
        float ya = __shfl_xor(a, s);
        float yb = __shfl_xor(b, s);
        if (lane & s) { a = ya - a; b = yb - b; }
        else          { a = a + ya; b = b + yb; }
    }
    const float c = 0.088388347648318447f;  // 1/sqrt(128)
    xb[base + lane]      = __float2bfloat16(a * c);
    xb[base + 64 + lane] = __float2bfloat16(b * c);
}

// ---------------- Trellis decode: tile -> bf16 W[out][in] (K-contiguous) ---
__global__ __launch_bounds__(256) void decode_k(const int* __restrict__ trellis,
                                                const float* __restrict__ tlut,
                                                const float* __restrict__ scales,
                                                __hip_bfloat16* __restrict__ wb) {
    __shared__ uint32_t w[32];
    const int nb = blockIdx.x;      // tile id: nb = tbx*256 + tby
    const int t = threadIdx.x;      // state index 0..255 within tile
    if (t < 32) w[t] = ((const uint32_t*)trellis)[(long)nb * 32 + t] & 0xFFFFu;
    __syncthreads();
    // 16-bit window starting at bit s=2t of the 512-bit big-endian stream
    const int q = t >> 3;           // word index = (2t)>>4
    const int r = (2 * t) & 15;     // bit offset in word
    // r==0 -> second term is w>>16 == 0 (w < 2^16), branchless
    const uint32_t state = ((w[q] << r) | (w[(q + 1) & 31] >> (16 - r))) & 0xFFFFu;

    const int tbx = nb >> 8;        // out-tile
    const int tby = nb & 255;       // in-tile
    const int row = t >> 4, col = t & 15;
    const int orow = tbx * 16 + row;
    const int icol = tby * 16 + col;
    // group of 128 along in_features: group = orow*32 + icol/128 = orow*32 + tby>>3
    const float v = tlut[state] * scales[orow * 32 + (tby >> 3)];
    wb[(long)orow * K_TOT + icol] = __float2bfloat16(v);
}

// ---------------- bf16 GEMM: C[m,n] = sum_k A[m,k]*B[n,k]  (both K-contig) --
// m97 structure: 128x128 block tile, BK=32, 256 threads (4 waves, 2x2),
// global_load_lds width-16 staging, mfma_f32_16x16x32_bf16, 4x4 tiles/wave.
__global__ __launch_bounds__(256) void gemm_k(const __hip_bfloat16* __restrict__ A,
                                              const __hip_bfloat16* __restrict__ B,
                                              float* __restrict__ C) {
    __shared__ __align__(16) __hip_bfloat16 sA[128 * 32];
    __shared__ __align__(16) __hip_bfloat16 sB[128 * 32];
    const int t = threadIdx.x;
    const int lane = t & 63;
    const int wave = t >> 6;
    const long m0 = (long)blockIdx.y * 128;
    const long n0 = (long)blockIdx.x * 128;

    // staging: thread t loads 16B = 8 bf16; row = t>>2 (+64 for 2nd call), seg = t&3
    const int srow = t >> 2;
    const int sseg = t & 3;
    const __hip_bfloat16* gA0 = A + (m0 + srow) * K_TOT + sseg * 8;
    const __hip_bfloat16* gA1 = gA0 + (long)64 * K_TOT;
    const __hip_bfloat16* gB0 = B + (n0 + srow) * K_TOT + sseg * 8;
    const __hip_bfloat16* gB1 = gB0 + (long)64 * K_TOT;
    // LDS dests: wave-uniform base + lane*16 (global_load_lds semantics)
    char* dA0 = (char*)sA + wave * 1024;
    char* dA1 = (char*)sA + 4096 + wave * 1024;
    char* dB0 = (char*)sB + wave * 1024;
    char* dB1 = (char*)sB + 4096 + wave * 1024;

    const int mtb = (wave & 1) * 64;   // wave's m-tile base within 128
    const int ntb = (wave >> 1) * 64;  // wave's n-tile base within 128
    const int lr = lane & 15;
    const int lq = lane >> 4;

    f32x4 acc[4][4] = {};

    for (int kk = 0; kk < K_TOT; kk += 32) {
        __builtin_amdgcn_global_load_lds(GLB(gA0 + kk), LDSP(dA0), 16, 0, 0);
        __builtin_amdgcn_global_load_lds(GLB(gA1 + kk), LDSP(dA1), 16, 0, 0);
        __builtin_amdgcn_global_load_lds(GLB(gB0 + kk), LDSP(dB0), 16, 0, 0);
        __builtin_amdgcn_global_load_lds(GLB(gB1 + kk), LDSP(dB1), 16, 0, 0);
        __syncthreads();

        bf16x8 af[4], bfr[4];
#pragma unroll
        for (int i = 0; i < 4; i++) {
            af[i]  = *(const bf16x8*)&sA[(mtb + i * 16 + lr) * 32 + lq * 8];
            bfr[i] = *(const bf16x8*)&sB[(ntb + i * 16 + lr) * 32 + lq * 8];
        }
#pragma unroll
        for (int i = 0; i < 4; i++)
#pragma unroll
            for (int j = 0; j < 4; j++)
                acc[i][j] = __builtin_amdgcn_mfma_f32_16x16x32_bf16(af[i], bfr[j], acc[i][j], 0, 0, 0);
        __syncthreads();
    }

    // C/D layout: col = lane&15, row = (lane>>4)*4 + reg
#pragma unroll
    for (int i = 0; i < 4; i++)
#pragma unroll
        for (int j = 0; j < 4; j++) {
            const long m = m0 + mtb + i * 16 + lq * 4;
            const long n = n0 + ntb + j * 16 + lr;
            float* cp = C + m * N_TOT + n;
#pragma unroll
            for (int r = 0; r < 4; r++)
                cp[(long)r * N_TOT] = acc[i][j][r];
        }
}

extern "C" void kernel_launch(void* const* d_in, const int* in_sizes, int n_in,
                              void* d_out, int out_size, void* d_ws, size_t ws_size,
                              hipStream_t stream) {
    const float* inp     = (const float*)d_in[0];   // (4,2048,4096) fp32
    const int*   trellis = (const int*)d_in[1];     // (65536,32) int32 (16-bit words)
    const float* tlut    = (const float*)d_in[2];   // (65536,1) fp32
    const float* scales  = (const float*)d_in[3];   // (131072,1) fp32
    float* out = (float*)d_out;                     // (4,2048,4096) fp32

    __hip_bfloat16* xb = (__hip_bfloat16*)d_ws;               // 8192*4096 bf16 = 64 MB
    __hip_bfloat16* wb = xb + (size_t)MROWS * K_TOT;          // 4096*4096 bf16 = 32 MB

    hipLaunchKernelGGL(hadamard_k, dim3(65536), dim3(256), 0, stream, inp, xb);
    hipLaunchKernelGGL(decode_k, dim3(65536), dim3(256), 0, stream, trellis, tlut, scales, wb);
    hipLaunchKernelGGL(gemm_k, dim3(N_TOT / 128, MROWS / 128), dim3(256), 0, stream, xb, wb, out);
}

// Round 2
// 652.608 us; speedup vs baseline: 1.0436x; 1.0436x over previous
//
#include <hip/hip_runtime.h>
#include <hip/hip_bf16.h>
#include <stdint.h>

// Problem constants (QuantizedLinear_22849226015470)
#define MROWS 8192      // 4*2048 activation rows
#define K_TOT 4096      // in_features
#define N_TOT 4096      // out_features
// trellis: NB=65536 tiles (256 x 256 of 16x16), 32 x 16-bit words per tile
// state_t = 16-bit big-endian window starting at bit 2t (circular, 512-bit)

typedef __attribute__((ext_vector_type(8))) short bf16x8;
typedef __attribute__((ext_vector_type(4))) float f32x4;

#define GLB(p) ((const __attribute__((address_space(1))) void*)(p))
#define LDSP(p) ((__attribute__((address_space(3))) void*)(p))

#define HAD_BLOCKS 32768   // 262144 groups / 8 per block
#define DEC_BLOCKS 16384   // 65536 tiles / 4 per block

// ---------------- Fused prep: hadamard rotate + trellis decode -------------
// blocks [0, HAD_BLOCKS): FWHT-128 on activations, fp32 -> bf16 (xb)
//   4 elems/lane, 2 groups/wave: stages 1,2 lane-local; stages 4..64 shuffles.
// blocks [HAD_BLOCKS, HAD_BLOCKS+DEC_BLOCKS): decode 4 weight tiles/block,
//   4 states/thread (ILP on the tlut gathers), packed bf16x4 stores.
__global__ __launch_bounds__(256) void prep_k(const float* __restrict__ in,
                                              const int* __restrict__ trellis,
                                              const float* __restrict__ tlut,
                                              const float* __restrict__ scales,
                                              __hip_bfloat16* __restrict__ xb,
                                              __hip_bfloat16* __restrict__ wb) {
    const int tid = threadIdx.x;
    if (blockIdx.x < HAD_BLOCKS) {
        // ---- Hadamard ----
        const int lane = tid & 63;
        const int wave = tid >> 6;
        const int half = lane >> 5;            // which group within the wave-pair
        const int l = lane & 31;               // lane within 32-half
        const long g = (long)blockIdx.x * 8 + wave * 2 + half;
        const long base = g * 128 + l * 4;
        float4 x = *(const float4*)(in + base);
        // stage 1 (lane-local)
        float t0 = x.x + x.y, t1 = x.x - x.y, t2 = x.z + x.w, t3 = x.z - x.w;
        // stage 2 (lane-local)
        float a = t0 + t2, c = t0 - t2, b = t1 + t3, d = t1 - t3;
        // stages 4..64: partner lane = lane ^ (s>>2), sign by (lane & (s>>2))
#pragma unroll
        for (int sh = 1; sh <= 16; sh <<= 1) {
            float pa = __shfl_xor(a, sh);
            float pb = __shfl_xor(b, sh);
            float pc = __shfl_xor(c, sh);
            float pd = __shfl_xor(d, sh);
            if (lane & sh) { a = pa - a; b = pb - b; c = pc - c; d = pd - d; }
            else           { a = a + pa; b = b + pb; c = c + pc; d = d + pd; }
        }
        const float cs = 0.088388347648318447f;  // 1/sqrt(128)
        __hip_bfloat16 h0 = __float2bfloat16(a * cs);
        __hip_bfloat16 h1 = __float2bfloat16(b * cs);
        __hip_bfloat16 h2 = __float2bfloat16(c * cs);
        __hip_bfloat16 h3 = __float2bfloat16(d * cs);
        ushort4 u;
        u.x = *(unsigned short*)&h0; u.y = *(unsigned short*)&h1;
        u.z = *(unsigned short*)&h2; u.w = *(unsigned short*)&h3;
        *(ushort4*)((unsigned short*)xb + base) = u;
    } else {
        // ---- Decode ----
        __shared__ uint32_t w[128];            // 4 tiles x 32 words
        const int d = blockIdx.x - HAD_BLOCKS;
        // stage trellis words: 32 threads x 16B
        if (tid < 32) {
            int4 v = *(const int4*)(trellis + (long)d * 128 + tid * 4);
            w[tid * 4 + 0] = (uint32_t)v.x & 0xFFFFu;
            w[tid * 4 + 1] = (uint32_t)v.y & 0xFFFFu;
            w[tid * 4 + 2] = (uint32_t)v.z & 0xFFFFu;
            w[tid * 4 + 3] = (uint32_t)v.w & 0xFFFFu;
        }
        __syncthreads();
        const int q4 = tid >> 6;               // tile within block (0..3)
        const int tl = tid & 63;
        const int r = tl >> 2;                 // row in tile (0..15)
        const int c4 = (tl & 3) * 4;           // col base (0,4,8,12)
        const int nb = d * 4 + q4;
        const int tbx = nb >> 8;               // out-tile
        const int tby = nb & 255;              // in-tile
        const int bt = r * 16 + c4;            // base state index
        const int q = bt >> 3;                 // word index (constant over j)
        const int r0 = (2 * bt) & 15;          // bit offset (0 or 8)
        const uint32_t w0 = w[q4 * 32 + q];
        const uint32_t w1 = w[q4 * 32 + ((q + 1) & 31)];
        const float sc = scales[(tbx * 16 + r) * 32 + (tby >> 3)];
        ushort4 u;
        unsigned short* up = (unsigned short*)&u;
#pragma unroll
        for (int j = 0; j < 4; j++) {
            const int rj = r0 + 2 * j;         // 0..14
            const uint32_t state = ((w0 << rj) | (w1 >> (16 - rj))) & 0xFFFFu;
            __hip_bfloat16 h = __float2bfloat16(tlut[state] * sc);
            up[j] = *(unsigned short*)&h;
        }
        const long orow = tbx * 16 + r;
        *(ushort4*)((unsigned short*)wb + orow * K_TOT + tby * 16 + c4) = u;
    }
}

// ---------------- bf16 GEMM: C[m,n] = sum_k A[m,k]*B[n,k]  (both K-contig) --
// m97 structure: 128x128 block tile, BK=32, 256 threads (4 waves, 2x2),
// global_load_lds width-16 staging, mfma_f32_16x16x32_bf16, 4x4 tiles/wave.
__global__ __launch_bounds__(256) void gemm_k(const __hip_bfloat16* __restrict__ A,
                                              const __hip_bfloat16* __restrict__ B,
                                              float* __restrict__ C) {
    __shared__ __align__(16) __hip_bfloat16 sA[128 * 32];
    __shared__ __align__(16) __hip_bfloat16 sB[128 * 32];
    const int t = threadIdx.x;
    const int lane = t & 63;
    const int wave = t >> 6;
    const long m0 = (long)blockIdx.y * 128;
    const long n0 = (long)blockIdx.x * 128;

    // staging: thread t loads 16B = 8 bf16; row = t>>2 (+64 for 2nd call), seg = t&3
    const int srow = t >> 2;
    const int sseg = t & 3;
    const __hip_bfloat16* gA0 = A + (m0 + srow) * K_TOT + sseg * 8;
    const __hip_bfloat16* gA1 = gA0 + (long)64 * K_TOT;
    const __hip_bfloat16* gB0 = B + (n0 + srow) * K_TOT + sseg * 8;
    const __hip_bfloat16* gB1 = gB0 + (long)64 * K_TOT;
    // LDS dests: wave-uniform base + lane*16 (global_load_lds semantics)
    char* dA0 = (char*)sA + wave * 1024;
    char* dA1 = (char*)sA + 4096 + wave * 1024;
    char* dB0 = (char*)sB + wave * 1024;
    char* dB1 = (char*)sB + 4096 + wave * 1024;

    const int mtb = (wave & 1) * 64;   // wave's m-tile base within 128
    const int ntb = (wave >> 1) * 64;  // wave's n-tile base within 128
    const int lr = lane & 15;
    const int lq = lane >> 4;

    f32x4 acc[4][4] = {};

    for (int kk = 0; kk < K_TOT; kk += 32) {
        __builtin_amdgcn_global_load_lds(GLB(gA0 + kk), LDSP(dA0), 16, 0, 0);
        __builtin_amdgcn_global_load_lds(GLB(gA1 + kk), LDSP(dA1), 16, 0, 0);
        __builtin_amdgcn_global_load_lds(GLB(gB0 + kk), LDSP(dB0), 16, 0, 0);
        __builtin_amdgcn_global_load_lds(GLB(gB1 + kk), LDSP(dB1), 16, 0, 0);
        __syncthreads();

        bf16x8 af[4], bfr[4];
#pragma unroll
        for (int i = 0; i < 4; i++) {
            af[i]  = *(const bf16x8*)&sA[(mtb + i * 16 + lr) * 32 + lq * 8];
            bfr[i] = *(const bf16x8*)&sB[(ntb + i * 16 + lr) * 32 + lq * 8];
        }
#pragma unroll
        for (int i = 0; i < 4; i++)
#pragma unroll
            for (int j = 0; j < 4; j++)
                acc[i][j] = __builtin_amdgcn_mfma_f32_16x16x32_bf16(af[i], bfr[j], acc[i][j], 0, 0, 0);
        __syncthreads();
    }

    // C/D layout: col = lane&15, row = (lane>>4)*4 + reg
#pragma unroll
    for (int i = 0; i < 4; i++)
#pragma unroll
        for (int j = 0; j < 4; j++) {
            const long m = m0 + mtb + i * 16 + lq * 4;
            const long n = n0 + ntb + j * 16 + lr;
            float* cp = C + m * N_TOT + n;
#pragma unroll
            for (int r = 0; r < 4; r++)
                cp[(long)r * N_TOT] = acc[i][j][r];
        }
}

extern "C" void kernel_launch(void* const* d_in, const int* in_sizes, int n_in,
                              void* d_out, int out_size, void* d_ws, size_t ws_size,
                              hipStream_t stream) {
    const float* inp     = (const float*)d_in[0];   // (4,2048,4096) fp32
    const int*   trellis = (const int*)d_in[1];     // (65536,32) int32 (16-bit words)
    const float* tlut    = (const float*)d_in[2];   // (65536,1) fp32
    const float* scales  = (const float*)d_in[3];   // (131072,1) fp32
    float* out = (float*)d_out;                     // (4,2048,4096) fp32

    __hip_bfloat16* xb = (__hip_bfloat16*)d_ws;               // 8192*4096 bf16 = 64 MB
    __hip_bfloat16* wb = xb + (size_t)MROWS * K_TOT;          // 4096*4096 bf16 = 32 MB

    hipLaunchKernelGGL(prep_k, dim3(HAD_BLOCKS + DEC_BLOCKS), dim3(256), 0, stream,
                       inp, trellis, tlut, scales, xb, wb);
    hipLaunchKernelGGL(gemm_k, dim3(N_TOT / 128, MROWS / 128), dim3(256), 0, stream, xb, wb, out);
}

// Round 3
// 648.641 us; speedup vs baseline: 1.0499x; 1.0061x over previous
//
#include <hip/hip_runtime.h>
#include <hip/hip_bf16.h>
#include <stdint.h>

// Problem constants (QuantizedLinear_22849226015470)
#define MROWS 8192      // 4*2048 activation rows
#define K_TOT 4096      // in_features
#define N_TOT 4096      // out_features
// trellis: NB=65536 tiles (256 out-tiles x 256 in-tiles of 16x16), 32 x 16-bit
// words per tile; state_t = 16-bit big-endian window at bit 2t (circular 512).
//
// Identity used here: out = (x·(I⊗H))·Wˢᵀ = x·(Wˢ·(I⊗H))ᵀ  (H128 symmetric),
// and the per-(row,128-group) scale commutes with H within its group. So we
// rotate the decoded WEIGHTS via MFMA (H entries ±1, exact in bf16; 1/√128
// folded into the scale) and the activation path is a pure fp32→bf16 convert.

typedef __attribute__((ext_vector_type(8))) short bf16x8;
typedef __attribute__((ext_vector_type(4))) float f32x4;
typedef __attribute__((ext_vector_type(8))) unsigned short ushort8;

#define GLB(p) ((const __attribute__((address_space(1))) void*)(p))
#define LDSP(p) ((__attribute__((address_space(3))) void*)(p))

#define CONV_BLOCKS 16384  // 33.5M elems / (256 thr * 8 elems)
#define DEC_BLOCKS  2048   // 8192 strips (16 rows x 128 cols) / 4 per block

// ---------------- Fused prep -----------------------------------------------
// blocks [0, CONV_BLOCKS): fp32 -> bf16 convert of activations (pure BW).
// blocks [CONV_BLOCKS, +DEC_BLOCKS): decode 4 strips (one per wave); each
//   strip = 16 out-rows x 128 in-cols; rotate by H128 via mfma_16x16x32_bf16;
//   scale*(1/sqrt(128)) in fp32 epilogue; store bf16 W''.
__global__ __launch_bounds__(256) void prep_k(const float* __restrict__ in,
                                              const int* __restrict__ trellis,
                                              const float* __restrict__ tlut,
                                              const float* __restrict__ scales,
                                              __hip_bfloat16* __restrict__ xb,
                                              __hip_bfloat16* __restrict__ wb) {
    const int tid = threadIdx.x;
    if (blockIdx.x < CONV_BLOCKS) {
        // ---- activation convert: 8 elems/thread, 16B in / 16B out ----
        const long base = ((long)blockIdx.x * 256 + tid) * 8;
        float4 x0 = *(const float4*)(in + base);
        float4 x1 = *(const float4*)(in + base + 4);
        ushort8 u;
        __hip_bfloat16 h;
        h = __float2bfloat16(x0.x); u[0] = *(unsigned short*)&h;
        h = __float2bfloat16(x0.y); u[1] = *(unsigned short*)&h;
        h = __float2bfloat16(x0.z); u[2] = *(unsigned short*)&h;
        h = __float2bfloat16(x0.w); u[3] = *(unsigned short*)&h;
        h = __float2bfloat16(x1.x); u[4] = *(unsigned short*)&h;
        h = __float2bfloat16(x1.y); u[5] = *(unsigned short*)&h;
        h = __float2bfloat16(x1.z); u[6] = *(unsigned short*)&h;
        h = __float2bfloat16(x1.w); u[7] = *(unsigned short*)&h;
        *(ushort8*)((unsigned short*)xb + base) = u;
    } else {
        // ---- decode + rotate ----
        __shared__ uint32_t sw[1024];                  // 32 tiles x 32 words
        __shared__ __hip_bfloat16 Hs[128 * 136];       // H[n][k], +8 pad
        const int b = blockIdx.x - CONV_BLOCKS;
        const int tbx = b >> 3;            // out-row tile (0..255)
        const int g0 = (b & 7) * 4;        // first 128-group of this block
        // stage trellis words: 32 consecutive tiles, one int4 per thread
        {
            int4 v = *((const int4*)(trellis + ((long)tbx * 256 + g0 * 8) * 32) + tid);
            sw[tid * 4 + 0] = (uint32_t)v.x & 0xFFFFu;
            sw[tid * 4 + 1] = (uint32_t)v.y & 0xFFFFu;
            sw[tid * 4 + 2] = (uint32_t)v.z & 0xFFFFu;
            sw[tid * 4 + 3] = (uint32_t)v.w & 0xFFFFu;
        }
        // stage H (±1, exact in bf16): Hs[n][k] = (-1)^popc(n&k)
        {
            const int n = tid >> 1;
            const int k0 = (tid & 1) * 64;
            const unsigned short pos = 0x3F80, neg = 0xBF80;
#pragma unroll 8
            for (int k = 0; k < 64; k++) {
                unsigned short s = (__popc(n & (k0 + k)) & 1) ? neg : pos;
                *((unsigned short*)Hs + n * 136 + k0 + k) = s;
            }
        }
        __syncthreads();

        const int wave = tid >> 6;         // strip within block
        const int lane = tid & 63;
        const int m = lane & 15;           // out-row within strip
        const int quad = lane >> 4;
        const int g = g0 + wave;           // 128-group index (0..31)

        // decode A-fragments: af[kc] holds Wdec[m][kc*32 + quad*8 + j]
        bf16x8 af[4];
#pragma unroll
        for (int kc = 0; kc < 4; kc++) {
            float v[8];
#pragma unroll
            for (int j = 0; j < 8; j++) {
                const int k = kc * 32 + quad * 8 + j;   // col within strip
                const int tile = wave * 8 + (k >> 4);   // tile in LDS
                const int c = k & 15;                   // col within tile
                const int t = m * 16 + c;               // state index
                const int q = t >> 3;                   // word index
                const int rb = (c & 7) * 2;             // bit offset (even)
                const uint32_t w0 = sw[tile * 32 + q];
                const uint32_t w1 = sw[tile * 32 + ((q + 1) & 31)];
                const uint32_t st = ((w0 << rb) | (w1 >> (16 - rb))) & 0xFFFFu;
                v[j] = tlut[st];
            }
#pragma unroll
            for (int j = 0; j < 8; j++) {
                __hip_bfloat16 h = __float2bfloat16(v[j]);
                af[kc][j] = *(short*)&h;
            }
        }
        // per-lane output-row scales (row = quad*4 + reg), 1/sqrt(128) folded
        float scl[4];
#pragma unroll
        for (int r = 0; r < 4; r++)
            scl[r] = scales[(tbx * 16 + quad * 4 + r) * 32 + g] * 0.088388347648318447f;

        // rotate: for each 16-col output tile, C = Wdec(16x128) · H-frags
#pragma unroll
        for (int nt = 0; nt < 8; nt++) {
            f32x4 c = {};
#pragma unroll
            for (int kc = 0; kc < 4; kc++) {
                bf16x8 bf = *(const bf16x8*)&Hs[(nt * 16 + m) * 136 + kc * 32 + quad * 8];
                c = __builtin_amdgcn_mfma_f32_16x16x32_bf16(af[kc], bf, c, 0, 0, 0);
            }
            const long col = (long)g * 128 + nt * 16 + m;   // C/D: col = lane&15
#pragma unroll
            for (int r = 0; r < 4; r++) {
                const long orow = tbx * 16 + quad * 4 + r;  // C/D: row = quad*4+reg
                wb[orow * K_TOT + col] = __float2bfloat16(c[r] * scl[r]);
            }
        }
    }
}

// ---------------- bf16 GEMM: C[m,n] = sum_k A[m,k]*B[n,k]  (both K-contig) --
// m97 structure: 128x128 block tile, BK=32, 256 threads (4 waves, 2x2),
// global_load_lds width-16 staging, mfma_f32_16x16x32_bf16, 4x4 tiles/wave.
__global__ __launch_bounds__(256) void gemm_k(const __hip_bfloat16* __restrict__ A,
                                              const __hip_bfloat16* __restrict__ B,
                                              float* __restrict__ C) {
    __shared__ __align__(16) __hip_bfloat16 sA[128 * 32];
    __shared__ __align__(16) __hip_bfloat16 sB[128 * 32];
    const int t = threadIdx.x;
    const int lane = t & 63;
    const int wave = t >> 6;
    const long m0 = (long)blockIdx.y * 128;
    const long n0 = (long)blockIdx.x * 128;

    const int srow = t >> 2;
    const int sseg = t & 3;
    const __hip_bfloat16* gA0 = A + (m0 + srow) * K_TOT + sseg * 8;
    const __hip_bfloat16* gA1 = gA0 + (long)64 * K_TOT;
    const __hip_bfloat16* gB0 = B + (n0 + srow) * K_TOT + sseg * 8;
    const __hip_bfloat16* gB1 = gB0 + (long)64 * K_TOT;
    char* dA0 = (char*)sA + wave * 1024;
    char* dA1 = (char*)sA + 4096 + wave * 1024;
    char* dB0 = (char*)sB + wave * 1024;
    char* dB1 = (char*)sB + 4096 + wave * 1024;

    const int mtb = (wave & 1) * 64;
    const int ntb = (wave >> 1) * 64;
    const int lr = lane & 15;
    const int lq = lane >> 4;

    f32x4 acc[4][4] = {};

    for (int kk = 0; kk < K_TOT; kk += 32) {
        __builtin_amdgcn_global_load_lds(GLB(gA0 + kk), LDSP(dA0), 16, 0, 0);
        __builtin_amdgcn_global_load_lds(GLB(gA1 + kk), LDSP(dA1), 16, 0, 0);
        __builtin_amdgcn_global_load_lds(GLB(gB0 + kk), LDSP(dB0), 16, 0, 0);
        __builtin_amdgcn_global_load_lds(GLB(gB1 + kk), LDSP(dB1), 16, 0, 0);
        __syncthreads();

        bf16x8 af[4], bfr[4];
#pragma unroll
        for (int i = 0; i < 4; i++) {
            af[i]  = *(const bf16x8*)&sA[(mtb + i * 16 + lr) * 32 + lq * 8];
            bfr[i] = *(const bf16x8*)&sB[(ntb + i * 16 + lr) * 32 + lq * 8];
        }
#pragma unroll
        for (int i = 0; i < 4; i++)
#pragma unroll
            for (int j = 0; j < 4; j++)
                acc[i][j] = __builtin_amdgcn_mfma_f32_16x16x32_bf16(af[i], bfr[j], acc[i][j], 0, 0, 0);
        __syncthreads();
    }

#pragma unroll
    for (int i = 0; i < 4; i++)
#pragma unroll
        for (int j = 0; j < 4; j++) {
            const long m = m0 + mtb + i * 16 + lq * 4;
            const long n = n0 + ntb + j * 16 + lr;
            float* cp = C + m * N_TOT + n;
#pragma unroll
            for (int r = 0; r < 4; r++)
                cp[(long)r * N_TOT] = acc[i][j][r];
        }
}

extern "C" void kernel_launch(void* const* d_in, const int* in_sizes, int n_in,
                              void* d_out, int out_size, void* d_ws, size_t ws_size,
                              hipStream_t stream) {
    const float* inp     = (const float*)d_in[0];   // (4,2048,4096) fp32
    const int*   trellis = (const int*)d_in[1];     // (65536,32) int32 (16-bit words)
    const float* tlut    = (const float*)d_in[2];   // (65536,1) fp32
    const float* scales  = (const float*)d_in[3];   // (131072,1) fp32
    float* out = (float*)d_out;                     // (4,2048,4096) fp32

    __hip_bfloat16* xb = (__hip_bfloat16*)d_ws;               // 64 MB
    __hip_bfloat16* wb = xb + (size_t)MROWS * K_TOT;          // 32 MB

    hipLaunchKernelGGL(prep_k, dim3(CONV_BLOCKS + DEC_BLOCKS), dim3(256), 0, stream,
                       inp, trellis, tlut, scales, xb, wb);
    hipLaunchKernelGGL(gemm_k, dim3(N_TOT / 128, MROWS / 128), dim3(256), 0, stream, xb, wb, out);
}